// Round 16
// baseline (246.585 us; speedup 1.0000x reference)
//
#include <hip/hip_runtime.h>

// ---------------------------------------------------------------------------
// CapsuleSequenceToGraph, fp32 in/out. B=64, T={128,512,256,256}, n=32, d=16.
// Identity: b_k[b,t,n] = <Vcum_k[b,n,:], pri[b,t,n,:]>, Vcum_k = sum_{i<k} v_i.
//
// pri ws layout (bf16), per mod: [b][t][n*16+d]  (B-MAJOR).
//
// Two kernels:
//   1) pri_kernel: pri = x @ W (bf16 MFMA). UNCHANGED (not critical path).
//   2) route_kernel: ONE block per (mod,b) pair (256 blocks, 1024 thr).
//      Rounds 4/7/11/13 proved prefetch/layout/liveness variants invariant
//      (56.5-58.9us, VALUBusy 28%): bottleneck is the PER-ROW SERIAL CHAIN
//      (dot -> 5 sequential shfl_xor -> exp -> div ≈ 2200 elapsed cyc/row
//      vs 150 issue-cyc; 4 same-phase waves contend for DS/trans pipes).
//      NOW: 4 rows per group-iteration with PHASED softmax — 4 independent
//      dots, 4 exps, 5 shuffle levels x4 independent lanes, 4 divs, 4 acc
//      updates. Chain latency amortized 4x within each wave.
// ---------------------------------------------------------------------------

typedef __attribute__((ext_vector_type(8))) short short8;
typedef __attribute__((ext_vector_type(4))) float floatx4;

static __device__ __forceinline__ unsigned short f2bf(float f) {
  union { float f; unsigned int i; } v;
  v.f = f;
  unsigned int x = v.i;
  return (unsigned short)((x + 0x7fffu + ((x >> 16) & 1u)) >> 16);  // RNE
}

// ---------------------------------------------------------------------------
// pri = x @ W, bf16 MFMA 16x16x32. Block = (t-pair, half): per t, M=64(b) x
// N=256(nd) x K=64(j). 1152 blocks. LDS 53KB -> 3 blocks/CU.
// ---------------------------------------------------------------------------
__global__ __launch_bounds__(256, 3) void pri_kernel(
    const float* __restrict__ x0, const float* __restrict__ x1,
    const float* __restrict__ x2, const float* __restrict__ x3,
    const float* __restrict__ w0, const float* __restrict__ w1,
    const float* __restrict__ w2, const float* __restrict__ w3,
    unsigned short* __restrict__ priAll) {
  __shared__ unsigned short wb[256 * 72];   // [nd_local][j] bf16, pitch 72
  __shared__ unsigned short sc[4][16][136]; // per-wave store-transpose scratch

  int blk = blockIdx.x;
  int tid = threadIdx.x;

  int pair = blk >> 1, half = blk & 1;
  const float* x;
  const float* W;
  unsigned short* priM;
  int T, t0;
  if (pair < 64)       { x = x0; W = w0; priM = priAll;               T = 128; t0 = 2 * pair; }
  else if (pair < 320) { x = x1; W = w1; priM = priAll + 4194304ull;  T = 512; t0 = 2 * (pair - 64); }
  else if (pair < 448) { x = x2; W = w2; priM = priAll + 20971520ull; T = 256; t0 = 2 * (pair - 320); }
  else                 { x = x3; W = w3; priM = priAll + 29360128ull; T = 256; t0 = 2 * (pair - 448); }
  size_t TS = (size_t)T * 512;  // b-row stride in shorts ([b][t][nd] layout)

  int lane = tid & 63, mt = tid >> 6;
  int m = lane & 15, q = lane >> 4;

  // ---- issue x loads for BOTH t (8 x floatx4, in flight together) ----
  floatx4 xv[8];
  {
    const float* xrow = x + ((size_t)(mt * 16 + m) * T + t0) * 64;
#pragma unroll
    for (int tt = 0; tt < 2; ++tt)
#pragma unroll
      for (int s = 0; s < 2; ++s) {
        const floatx4* xp = (const floatx4*)(xrow + tt * 64 + s * 32 + q * 8);
        xv[tt * 4 + s * 2]     = __builtin_nontemporal_load(xp);
        xv[tt * 4 + s * 2 + 1] = __builtin_nontemporal_load(xp + 1);
      }
  }

  // ---- issue W(t0) loads: 16 floatx4 explicitly in flight ----
  floatx4 wra[8], wrb[8];
  {
    const floatx4* Wf = (const floatx4*)(W + (size_t)t0 * 32768);
#pragma unroll
    for (int it = 0; it < 8; ++it) {
      int idx = it * 256 + tid;              // 0..2047
      int nl = idx >> 7, jp = (idx >> 2) & 31, dq = idx & 3;
      int ng = half * 16 + nl;
      wra[it] = __builtin_nontemporal_load(Wf + ng * 256 + (2 * jp) * 4 + dq);
      wrb[it] = __builtin_nontemporal_load(Wf + ng * 256 + (2 * jp + 1) * 4 + dq);
    }
  }

  // ---- build A fragments for both t while W loads fly ----
  short8 afrag[2][2];  // [tt][s]
#pragma unroll
  for (int tt = 0; tt < 2; ++tt)
#pragma unroll
    for (int s = 0; s < 2; ++s) {
      floatx4 u0 = xv[tt * 4 + s * 2], u1 = xv[tt * 4 + s * 2 + 1];
      short8 a;
      a[0] = (short)f2bf(u0[0]); a[1] = (short)f2bf(u0[1]);
      a[2] = (short)f2bf(u0[2]); a[3] = (short)f2bf(u0[3]);
      a[4] = (short)f2bf(u1[0]); a[5] = (short)f2bf(u1[1]);
      a[6] = (short)f2bf(u1[2]); a[7] = (short)f2bf(u1[3]);
      afrag[tt][s] = a;
    }

  unsigned int* wb32 = (unsigned int*)wb;  // pitch 36 dwords

  // ---- convert + write wb(t0) ----
#pragma unroll
  for (int it = 0; it < 8; ++it) {
    int idx = it * 256 + tid;
    int nl = idx >> 7, jp = (idx >> 2) & 31, dq = idx & 3;
    int rbase = nl * 16 + dq * 4;
#pragma unroll
    for (int k = 0; k < 4; ++k) {
      unsigned int dw = (unsigned int)f2bf(wra[it][k]) | ((unsigned int)f2bf(wrb[it][k]) << 16);
      wb32[(rbase + k) * 36 + jp] = dw;
    }
  }
  __syncthreads();

  // ---- issue W(t1) loads NOW; they stay in VGPRs across t0 compute ----
  {
    const floatx4* Wf = (const floatx4*)(W + (size_t)(t0 + 1) * 32768);
#pragma unroll
    for (int it = 0; it < 8; ++it) {
      int idx = it * 256 + tid;
      int nl = idx >> 7, jp = (idx >> 2) & 31, dq = idx & 3;
      int ng = half * 16 + nl;
      wra[it] = __builtin_nontemporal_load(Wf + ng * 256 + (2 * jp) * 4 + dq);
      wrb[it] = __builtin_nontemporal_load(Wf + ng * 256 + (2 * jp + 1) * 4 + dq);
    }
  }

  // ---- compute one t: 16 N-tiles; D: row b = mt*16+q*4+reg, col nd = nt*16+m
  // store to [b][t][nd]: addr = b*TS + t*512 + nd
  auto compute_t = [&](const short8& a0, const short8& a1, int t) {
    unsigned short* dst = priM + (size_t)t * 512 + half * 256;
    for (int g2 = 0; g2 < 2; ++g2) {
#pragma unroll
      for (int k = 0; k < 8; ++k) {
        int nt = g2 * 8 + k;
        const short8* b0p = (const short8*)&wb[(nt * 16 + m) * 72 + q * 8];
        const short8* b1p = (const short8*)&wb[(nt * 16 + m) * 72 + 32 + q * 8];
        short8 bf0 = *b0p, bf1 = *b1p;
        floatx4 acc = {0.f, 0.f, 0.f, 0.f};
        acc = __builtin_amdgcn_mfma_f32_16x16x32_bf16(a0, bf0, acc, 0, 0, 0);
        acc = __builtin_amdgcn_mfma_f32_16x16x32_bf16(a1, bf1, acc, 0, 0, 0);
#pragma unroll
        for (int reg = 0; reg < 4; ++reg)
          sc[mt][q * 4 + reg][k * 16 + m] = f2bf(acc[reg]);
      }
#pragma unroll
      for (int i = 0; i < 4; ++i) {
        int bl = (lane >> 4) + i * 4;
        int sh = (lane & 15) * 8;
        short8 v = *(const short8*)&sc[mt][bl][sh];
        *(short8*)(dst + (size_t)(mt * 16 + bl) * TS + g2 * 128 + sh) = v;
      }
    }
  };

  compute_t(afrag[0][0], afrag[0][1], t0);
  __syncthreads();  // all waves done reading wb(t0)

  // ---- convert + write wb(t1) ----
#pragma unroll
  for (int it = 0; it < 8; ++it) {
    int idx = it * 256 + tid;
    int nl = idx >> 7, jp = (idx >> 2) & 31, dq = idx & 3;
    int rbase = nl * 16 + dq * 4;
#pragma unroll
    for (int k = 0; k < 4; ++k) {
      unsigned int dw = (unsigned int)f2bf(wra[it][k]) | ((unsigned int)f2bf(wrb[it][k]) << 16);
      wb32[(rbase + k) * 36 + jp] = dw;
    }
  }
  __syncthreads();

  compute_t(afrag[1][0], afrag[1][1], t0 + 1);
}

// ---------------------------------------------------------------------------
// route_kernel: block = one (mod, b) pair. 1024 threads = 32 groups of 32.
// Group g handles 4 rows per iteration: t = it*128 + g + {0,32,64,96}, with
// PHASED softmax (4 dots | 4 exps | 5 shuffle-levels x4 | 4 divs | 4 accs)
// to amortize the serial chain 4x. launch_bounds(1024,4) -> 128 VGPR cap.
// All 4 routing passes in-block; Vcum in LDS (pitch-17). Softmax without
// max-subtraction (|logit| bounded << fp32 exp range).
// LDS ~84KB -> exactly 1 block/CU (256 blocks on 256 CUs).
// ---------------------------------------------------------------------------
__global__ __launch_bounds__(1024, 4) void route_kernel(
    const unsigned short* __restrict__ priAll, float* __restrict__ out) {
  __shared__ float Sl[32][640];   // [group][n*17+d], pitch 640 (occupancy pin)
  __shared__ float Vc_s[544];     // Vcum, [n*17+d]

  int blk = blockIdx.x;
  int mod = blk & 3, b = blk >> 2;
  size_t poff; int T;
  if (mod == 0)      { poff = 0ull;         T = 128; }
  else if (mod == 1) { poff = 4194304ull;   T = 512; }
  else if (mod == 2) { poff = 20971520ull;  T = 256; }
  else               { poff = 29360128ull;  T = 256; }

  // [b][t][nd]: this block's slice is contiguous T KB
  const unsigned short* priM = priAll + poff + (size_t)b * T * 512;

  int tid = threadIdx.x;
  int n = tid & 31, g = tid >> 5;
  int nbase = n * 17;

  if (tid < 544) Vc_s[tid] = 0.f;
  __syncthreads();

  int iters4 = T >> 7;  // quad-row iterations per group per pass (>= 1)

  for (int pass = 0; pass < 4; ++pass) {
    float Vc[16];
#pragma unroll
    for (int d = 0; d < 16; ++d) Vc[d] = Vc_s[nbase + d];

    float acc[16];
#pragma unroll
    for (int d = 0; d < 16; ++d) acc[d] = 0.f;

    // rows t = it*128 + g + {0,32,64,96}; row = 64 uint4; 32 rows = 2048
    const uint4* pr = (const uint4*)(priM + (size_t)g * 512 + n * 16);

    for (int it = 0; it < iters4; ++it) {
      uint4 c0 = pr[0],    c1 = pr[1];       // row g+0
      uint4 c2 = pr[2048], c3 = pr[2049];    // row g+32
      uint4 c4 = pr[4096], c5 = pr[4097];    // row g+64
      uint4 c6 = pr[6144], c7 = pr[6145];    // row g+96

      // Phase A: 4 independent dots (unpack on the fly)
      float logit4[4];
#pragma unroll
      for (int r = 0; r < 4; ++r) {
        uint4 ca = (r == 0) ? c0 : (r == 1) ? c2 : (r == 2) ? c4 : c6;
        uint4 cb = (r == 0) ? c1 : (r == 1) ? c3 : (r == 2) ? c5 : c7;
        unsigned int wds[8] = {ca.x, ca.y, ca.z, ca.w, cb.x, cb.y, cb.z, cb.w};
        float lg = 0.f;
#pragma unroll
        for (int k = 0; k < 8; ++k) {
          union { unsigned int u; float f; } lo, hi;
          lo.u = wds[k] << 16;
          hi.u = wds[k] & 0xffff0000u;
          lg += lo.f * Vc[2 * k] + hi.f * Vc[2 * k + 1];
        }
        logit4[r] = lg;
      }

      // Phase B: 4 independent exps
      float e4[4];
#pragma unroll
      for (int r = 0; r < 4; ++r) e4[r] = __expf(logit4[r]);

      // Phase C: batched reduce — 5 levels, 4 independent shuffles per level
      float s4[4] = {e4[0], e4[1], e4[2], e4[3]};
#pragma unroll
      for (int o = 16; o >= 1; o >>= 1) {
        float u0 = __shfl_xor(s4[0], o, 32);
        float u1 = __shfl_xor(s4[1], o, 32);
        float u2 = __shfl_xor(s4[2], o, 32);
        float u3 = __shfl_xor(s4[3], o, 32);
        s4[0] += u0; s4[1] += u1; s4[2] += u2; s4[3] += u3;
      }

      // Phase D: 4 independent divides
      float rc4[4];
#pragma unroll
      for (int r = 0; r < 4; ++r) rc4[r] = e4[r] / s4[r];

      // Phase E: acc += rc*p (re-unpack; 16 parallel d-chains)
#pragma unroll
      for (int r = 0; r < 4; ++r) {
        uint4 ca = (r == 0) ? c0 : (r == 1) ? c2 : (r == 2) ? c4 : c6;
        uint4 cb = (r == 0) ? c1 : (r == 1) ? c3 : (r == 2) ? c5 : c7;
        unsigned int wds[8] = {ca.x, ca.y, ca.z, ca.w, cb.x, cb.y, cb.z, cb.w};
#pragma unroll
        for (int k = 0; k < 8; ++k) {
          union { unsigned int u; float f; } lo, hi;
          lo.u = wds[k] << 16;
          hi.u = wds[k] & 0xffff0000u;
          acc[2 * k]     += rc4[r] * lo.f;
          acc[2 * k + 1] += rc4[r] * hi.f;
        }
      }

      pr += 8192;  // +128 rows
    }

#pragma unroll
    for (int d = 0; d < 16; ++d) Sl[g][nbase + d] = acc[d];
    __syncthreads();

    if (tid < 512) {
      int nn = tid >> 4, dd = tid & 15;
      int idx = nn * 17 + dd;
      float s = 0.f;
#pragma unroll
      for (int gg = 0; gg < 32; ++gg) s += Sl[gg][idx];
      float v = tanhf(s);
      if (pass == 3) out[(size_t)(mod * 64 + b) * 512 + tid] = v;
      else Vc_s[idx] += v;
    }
    __syncthreads();
  }
}

extern "C" void kernel_launch(void* const* d_in, const int* in_sizes, int n_in,
                              void* d_out, int out_size, void* d_ws, size_t ws_size,
                              hipStream_t stream) {
  const float* x0 = (const float*)d_in[0];
  const float* x1 = (const float*)d_in[1];
  const float* x2 = (const float*)d_in[2];
  const float* x3 = (const float*)d_in[3];
  const float* w0 = (const float*)d_in[4];
  const float* w1 = (const float*)d_in[5];
  const float* w2 = (const float*)d_in[6];
  const float* w3 = (const float*)d_in[7];

  unsigned short* pri = (unsigned short*)d_ws;

  pri_kernel<<<1152, 256, 0, stream>>>(x0, x1, x2, x3, w0, w1, w2, w3, pri);
  route_kernel<<<256, 1024, 0, stream>>>(pri, (float*)d_out);
}

// Round 19
// 236.299 us; speedup vs baseline: 1.0435x; 1.0435x over previous
//
#include <hip/hip_runtime.h>

// ---------------------------------------------------------------------------
// CapsuleSequenceToGraph, fp32 in/out. B=64, T={128,512,256,256}, n=32, d=16.
// Identity: b_k[b,t,n] = <Vcum_k[b,n,:], pri[b,t,n,:]>, Vcum_k = sum_{i<k} v_i.
//
// pri ws layout (bf16), per mod: [b][t][n*16+d]  (B-MAJOR).
//
// ROUTE THEORY (rounds 4-16): all five schedule/MLP variants land 56.5-62.7us
// at VALUBusy 28% -> route is bound by memory-system byte delivery (~5.3 TB/s
// effective), NOT latency/ILP. Logical bytes = 4 passes x 75.5MB = 302MB.
// FIX: HYBRID RESIDENCY — pass 1 (rc uniform = 1/32, no softmax needed)
// stages 6 rows/group (3 in registers + 3 in LDS); passes 2-4 re-read only
// the remainder. Traffic/pair: text 512->128KB (fully resident), vf
// 1024->448KB, audio 2048->1472KB. Total ~160MB.
// ---------------------------------------------------------------------------

typedef __attribute__((ext_vector_type(8))) short short8;
typedef __attribute__((ext_vector_type(4))) float floatx4;

static __device__ __forceinline__ unsigned short f2bf(float f) {
  union { float f; unsigned int i; } v;
  v.f = f;
  unsigned int x = v.i;
  return (unsigned short)((x + 0x7fffu + ((x >> 16) & 1u)) >> 16);  // RNE
}

// ---------------------------------------------------------------------------
// pri = x @ W, bf16 MFMA 16x16x32. Block = (t-pair, half): per t, M=64(b) x
// N=256(nd) x K=64(j). 1152 blocks. LDS 53KB -> 3 blocks/CU. UNCHANGED.
// ---------------------------------------------------------------------------
__global__ __launch_bounds__(256, 3) void pri_kernel(
    const float* __restrict__ x0, const float* __restrict__ x1,
    const float* __restrict__ x2, const float* __restrict__ x3,
    const float* __restrict__ w0, const float* __restrict__ w1,
    const float* __restrict__ w2, const float* __restrict__ w3,
    unsigned short* __restrict__ priAll) {
  __shared__ unsigned short wb[256 * 72];   // [nd_local][j] bf16, pitch 72
  __shared__ unsigned short sc[4][16][136]; // per-wave store-transpose scratch

  int blk = blockIdx.x;
  int tid = threadIdx.x;

  int pair = blk >> 1, half = blk & 1;
  const float* x;
  const float* W;
  unsigned short* priM;
  int T, t0;
  if (pair < 64)       { x = x0; W = w0; priM = priAll;               T = 128; t0 = 2 * pair; }
  else if (pair < 320) { x = x1; W = w1; priM = priAll + 4194304ull;  T = 512; t0 = 2 * (pair - 64); }
  else if (pair < 448) { x = x2; W = w2; priM = priAll + 20971520ull; T = 256; t0 = 2 * (pair - 320); }
  else                 { x = x3; W = w3; priM = priAll + 29360128ull; T = 256; t0 = 2 * (pair - 448); }
  size_t TS = (size_t)T * 512;  // b-row stride in shorts ([b][t][nd] layout)

  int lane = tid & 63, mt = tid >> 6;
  int m = lane & 15, q = lane >> 4;

  // ---- issue x loads for BOTH t (8 x floatx4, in flight together) ----
  floatx4 xv[8];
  {
    const float* xrow = x + ((size_t)(mt * 16 + m) * T + t0) * 64;
#pragma unroll
    for (int tt = 0; tt < 2; ++tt)
#pragma unroll
      for (int s = 0; s < 2; ++s) {
        const floatx4* xp = (const floatx4*)(xrow + tt * 64 + s * 32 + q * 8);
        xv[tt * 4 + s * 2]     = __builtin_nontemporal_load(xp);
        xv[tt * 4 + s * 2 + 1] = __builtin_nontemporal_load(xp + 1);
      }
  }

  // ---- issue W(t0) loads: 16 floatx4 explicitly in flight ----
  floatx4 wra[8], wrb[8];
  {
    const floatx4* Wf = (const floatx4*)(W + (size_t)t0 * 32768);
#pragma unroll
    for (int it = 0; it < 8; ++it) {
      int idx = it * 256 + tid;              // 0..2047
      int nl = idx >> 7, jp = (idx >> 2) & 31, dq = idx & 3;
      int ng = half * 16 + nl;
      wra[it] = __builtin_nontemporal_load(Wf + ng * 256 + (2 * jp) * 4 + dq);
      wrb[it] = __builtin_nontemporal_load(Wf + ng * 256 + (2 * jp + 1) * 4 + dq);
    }
  }

  // ---- build A fragments for both t while W loads fly ----
  short8 afrag[2][2];  // [tt][s]
#pragma unroll
  for (int tt = 0; tt < 2; ++tt)
#pragma unroll
    for (int s = 0; s < 2; ++s) {
      floatx4 u0 = xv[tt * 4 + s * 2], u1 = xv[tt * 4 + s * 2 + 1];
      short8 a;
      a[0] = (short)f2bf(u0[0]); a[1] = (short)f2bf(u0[1]);
      a[2] = (short)f2bf(u0[2]); a[3] = (short)f2bf(u0[3]);
      a[4] = (short)f2bf(u1[0]); a[5] = (short)f2bf(u1[1]);
      a[6] = (short)f2bf(u1[2]); a[7] = (short)f2bf(u1[3]);
      afrag[tt][s] = a;
    }

  unsigned int* wb32 = (unsigned int*)wb;  // pitch 36 dwords

  // ---- convert + write wb(t0) ----
#pragma unroll
  for (int it = 0; it < 8; ++it) {
    int idx = it * 256 + tid;
    int nl = idx >> 7, jp = (idx >> 2) & 31, dq = idx & 3;
    int rbase = nl * 16 + dq * 4;
#pragma unroll
    for (int k = 0; k < 4; ++k) {
      unsigned int dw = (unsigned int)f2bf(wra[it][k]) | ((unsigned int)f2bf(wrb[it][k]) << 16);
      wb32[(rbase + k) * 36 + jp] = dw;
    }
  }
  __syncthreads();

  // ---- issue W(t1) loads NOW; they stay in VGPRs across t0 compute ----
  {
    const floatx4* Wf = (const floatx4*)(W + (size_t)(t0 + 1) * 32768);
#pragma unroll
    for (int it = 0; it < 8; ++it) {
      int idx = it * 256 + tid;
      int nl = idx >> 7, jp = (idx >> 2) & 31, dq = idx & 3;
      int ng = half * 16 + nl;
      wra[it] = __builtin_nontemporal_load(Wf + ng * 256 + (2 * jp) * 4 + dq);
      wrb[it] = __builtin_nontemporal_load(Wf + ng * 256 + (2 * jp + 1) * 4 + dq);
    }
  }

  // ---- compute one t: 16 N-tiles; D: row b = mt*16+q*4+reg, col nd = nt*16+m
  auto compute_t = [&](const short8& a0, const short8& a1, int t) {
    unsigned short* dst = priM + (size_t)t * 512 + half * 256;
    for (int g2 = 0; g2 < 2; ++g2) {
#pragma unroll
      for (int k = 0; k < 8; ++k) {
        int nt = g2 * 8 + k;
        const short8* b0p = (const short8*)&wb[(nt * 16 + m) * 72 + q * 8];
        const short8* b1p = (const short8*)&wb[(nt * 16 + m) * 72 + 32 + q * 8];
        short8 bf0 = *b0p, bf1 = *b1p;
        floatx4 acc = {0.f, 0.f, 0.f, 0.f};
        acc = __builtin_amdgcn_mfma_f32_16x16x32_bf16(a0, bf0, acc, 0, 0, 0);
        acc = __builtin_amdgcn_mfma_f32_16x16x32_bf16(a1, bf1, acc, 0, 0, 0);
#pragma unroll
        for (int reg = 0; reg < 4; ++reg)
          sc[mt][q * 4 + reg][k * 16 + m] = f2bf(acc[reg]);
      }
#pragma unroll
      for (int i = 0; i < 4; ++i) {
        int bl = (lane >> 4) + i * 4;
        int sh = (lane & 15) * 8;
        short8 v = *(const short8*)&sc[mt][bl][sh];
        *(short8*)(dst + (size_t)(mt * 16 + bl) * TS + g2 * 128 + sh) = v;
      }
    }
  };

  compute_t(afrag[0][0], afrag[0][1], t0);
  __syncthreads();  // all waves done reading wb(t0)

  // ---- convert + write wb(t1) ----
#pragma unroll
  for (int it = 0; it < 8; ++it) {
    int idx = it * 256 + tid;
    int nl = idx >> 7, jp = (idx >> 2) & 31, dq = idx & 3;
    int rbase = nl * 16 + dq * 4;
#pragma unroll
    for (int k = 0; k < 4; ++k) {
      unsigned int dw = (unsigned int)f2bf(wra[it][k]) | ((unsigned int)f2bf(wrb[it][k]) << 16);
      wb32[(rbase + k) * 36 + jp] = dw;
    }
  }
  __syncthreads();

  compute_t(afrag[1][0], afrag[1][1], t0 + 1);
}

// ---------------------------------------------------------------------------
// route_kernel: block = one (mod, b) pair. 1024 threads = 32 groups of 32.
// Group g owns rows t = q*32+g, q in [0,R), R = T/32 (4/16/8/8).
//   q=0..2  -> register-resident (named uint4s, static access)
//   q=3..5  -> LDS-resident (Ld, staged during pass 1; text has only q=3)
//   q>=6    -> streamed from global each pass (audio 10, vf 2, text 0)
// Pass 1: rc uniform (softmax of zeros) -> plain mean; stages residents.
// Partial reduce: wave-level shfl_xor(32) combine -> Sl[16] (34KB, frees
// LDS for the 101KB data buffer). Softmax without max-subtraction.
// LDS 138KB -> 1 block/CU. launch_bounds(1024,4) -> 128 VGPR cap.
// ---------------------------------------------------------------------------
__global__ __launch_bounds__(1024, 4) void route_kernel(
    const unsigned short* __restrict__ priAll, float* __restrict__ out) {
  __shared__ unsigned short Ld[96 * 528];  // 96 resident rows, pitch 528 shorts (101,376 B)
  __shared__ float Sl[16][544];            // wave-combined partials (34,816 B)
  __shared__ float Vc_s[544];              // Vcum, [n*17+d] (2,176 B)

  int blk = blockIdx.x;
  int mod = blk & 3, b = blk >> 2;
  size_t poff; int T;
  if (mod == 0)      { poff = 0ull;         T = 128; }
  else if (mod == 1) { poff = 4194304ull;   T = 512; }
  else if (mod == 2) { poff = 20971520ull;  T = 256; }
  else               { poff = 29360128ull;  T = 256; }

  const unsigned short* priM = priAll + poff + (size_t)b * T * 512;

  int tid = threadIdx.x;
  int n = tid & 31, g = tid >> 5;
  int wv = tid >> 6;               // wave index [0,16)
  int nbase = n * 17;
  int R = T >> 5;                  // rows per group (4,16,8,8)
  int nlds = (R >= 6) ? 3 : (R - 3);
  int nglob = (R > 6) ? (R - 6) : 0;

  if (tid < 544) Vc_s[tid] = 0.f;
  __syncthreads();

  // row t = q*32+g base, in uint4 units (row = 64 uint4; +32 rows = 2048)
  const uint4* base = (const uint4*)(priM + (size_t)g * 512 + n * 16);

  float acc[16];
  uint4 r0a, r0b, r1a, r1b, r2a, r2b;  // register-resident rows q=0,1,2

  auto accum_row = [&](uint4 a, uint4 c) {
    unsigned int wds[8] = {a.x, a.y, a.z, a.w, c.x, c.y, c.z, c.w};
#pragma unroll
    for (int k = 0; k < 8; ++k) {
      union { unsigned int u; float f; } lo, hi;
      lo.u = wds[k] << 16;
      hi.u = wds[k] & 0xffff0000u;
      acc[2 * k]     += lo.f;
      acc[2 * k + 1] += hi.f;
    }
  };

  // epilogue: wave-combine, block reduce, v = tanh(S), Vcum += v / out
  auto epilogue = [&](int pass) {
#pragma unroll
    for (int d = 0; d < 16; ++d) acc[d] += __shfl_xor(acc[d], 32, 64);
    if ((tid & 63) < 32) {
#pragma unroll
      for (int d = 0; d < 16; ++d) Sl[wv][nbase + d] = acc[d];
    }
    __syncthreads();
    if (tid < 512) {
      int idx = (tid >> 4) * 17 + (tid & 15);
      float s = 0.f;
#pragma unroll
      for (int w = 0; w < 16; ++w) s += Sl[w][idx];
      float v = tanhf(s);
      if (pass == 3) out[(size_t)(mod * 64 + b) * 512 + tid] = v;
      else Vc_s[idx] += v;
    }
    __syncthreads();
  };

  // ---------------- PASS 0: rc = 1/32 uniform; stage residents ----------------
#pragma unroll
  for (int d = 0; d < 16; ++d) acc[d] = 0.f;

  r0a = base[0];    r0b = base[1];
  r1a = base[2048]; r1b = base[2049];
  r2a = base[4096]; r2b = base[4097];
  accum_row(r0a, r0b);
  accum_row(r1a, r1b);
  accum_row(r2a, r2b);

  for (int i = 0; i < nlds; ++i) {
    uint4 a = base[(3 + i) * 2048], c = base[(3 + i) * 2048 + 1];
    uint4* ldp = (uint4*)&Ld[(i * 32 + g) * 528 + n * 16];
    ldp[0] = a; ldp[1] = c;
    accum_row(a, c);
  }
  for (int i = 0; i < nglob; ++i) {
    uint4 a = base[(6 + i) * 2048], c = base[(6 + i) * 2048 + 1];
    accum_row(a, c);
  }
#pragma unroll
  for (int d = 0; d < 16; ++d) acc[d] *= 0.03125f;  // rc = 1/32 exact
  epilogue(0);

  // ---------------- PASSES 1..3: logit -> softmax -> weighted acc -------------
  for (int pass = 1; pass < 4; ++pass) {
    float Vc[16];
#pragma unroll
    for (int d = 0; d < 16; ++d) Vc[d] = Vc_s[nbase + d];
#pragma unroll
    for (int d = 0; d < 16; ++d) acc[d] = 0.f;

    auto proc_row = [&](uint4 a, uint4 c) {
      float p[16];
      {
        unsigned int wds[8] = {a.x, a.y, a.z, a.w, c.x, c.y, c.z, c.w};
#pragma unroll
        for (int k = 0; k < 8; ++k) {
          union { unsigned int u; float f; } lo, hi;
          lo.u = wds[k] << 16;
          hi.u = wds[k] & 0xffff0000u;
          p[2 * k] = lo.f;
          p[2 * k + 1] = hi.f;
        }
      }
      float logit = 0.f;
#pragma unroll
      for (int d = 0; d < 16; ++d) logit += p[d] * Vc[d];
      float e = __expf(logit);
      float s = e;
#pragma unroll
      for (int o = 16; o >= 1; o >>= 1) s += __shfl_xor(s, o, 32);
      float rc = e / s;
#pragma unroll
      for (int d = 0; d < 16; ++d) acc[d] += rc * p[d];
    };

    proc_row(r0a, r0b);
    proc_row(r1a, r1b);
    proc_row(r2a, r2b);
    for (int i = 0; i < nlds; ++i) {
      const uint4* ldp = (const uint4*)&Ld[(i * 32 + g) * 528 + n * 16];
      proc_row(ldp[0], ldp[1]);
    }
    for (int i = 0; i < nglob; ++i) {
      uint4 a = base[(6 + i) * 2048], c = base[(6 + i) * 2048 + 1];
      proc_row(a, c);
    }
    epilogue(pass);
  }
}

extern "C" void kernel_launch(void* const* d_in, const int* in_sizes, int n_in,
                              void* d_out, int out_size, void* d_ws, size_t ws_size,
                              hipStream_t stream) {
  const float* x0 = (const float*)d_in[0];
  const float* x1 = (const float*)d_in[1];
  const float* x2 = (const float*)d_in[2];
  const float* x3 = (const float*)d_in[3];
  const float* w0 = (const float*)d_in[4];
  const float* w1 = (const float*)d_in[5];
  const float* w2 = (const float*)d_in[6];
  const float* w3 = (const float*)d_in[7];

  unsigned short* pri = (unsigned short*)d_ws;

  pri_kernel<<<1152, 256, 0, stream>>>(x0, x1, x2, x3, w0, w1, w2, w3, pri);
  route_kernel<<<256, 1024, 0, stream>>>(pri, (float*)d_out);
}